// Round 8
// baseline (320.383 us; speedup 1.0000x reference)
//
#include <hip/hip_runtime.h>
#include <hip/hip_bf16.h>
#include <hip/hip_cooperative_groups.h>

namespace cg = cooperative_groups;

// Problem constants
constexpr int NN    = 4096;     // nodes
constexpr int EE    = 131072;   // edges
constexpr int IN_F  = 256;
constexpr int OUT_F = 64;
constexpr int HH    = 8;
constexpr int HF    = OUT_F * HH;   // 512
constexpr int CAP   = 128;          // CSR capacity (raw deg: mean 32, 17-sigma < 128)

constexpr int GRID  = 512;          // blocks (cooperative, 2/CU)
constexpr int BLK   = 256;          // threads per block

// f32 -> bf16 round-to-nearest-even
__device__ __forceinline__ unsigned short f2b(float f) {
    unsigned int u = __float_as_uint(f);
    u = u + 0x7FFFu + ((u >> 16) & 1u);
    return (unsigned short)(u >> 16);
}
// bf16 (as u16) -> f32 (exact)
__device__ __forceinline__ float b2f(unsigned int lo16) {
    return __uint_as_float(lo16 << 16);
}

#define TM 64
#define TN 64
#define TK 32

// ---------------------------------------------------------------------------
// Mega-kernel: phase0 zero | phase1 scatter | phase2 GEMM+epilogue | phase3 agg
// grid.sync() between phases (cooperative launch).
// ---------------------------------------------------------------------------
__global__ __launch_bounds__(BLK) void gat_mega(const float* __restrict__ x,
                                                const float* __restrict__ W,
                                                const float* __restrict__ a,
                                                const int* __restrict__ src,
                                                const int* __restrict__ dst,
                                                unsigned short* __restrict__ Whb,
                                                float* __restrict__ asrc,
                                                float* __restrict__ adst,
                                                float* __restrict__ S,
                                                int* __restrict__ cnt,
                                                int* __restrict__ csr_dst,
                                                float* __restrict__ out) {
    cg::grid_group grid = cg::this_grid();
    int b = blockIdx.x;
    int t = threadIdx.x;
    int gt = b * BLK + t;   // 0 .. 131071

    // ---------------- phase 0: zero cnt + S ----------------
    if (gt < NN) cnt[gt] = 0;
    if (gt >= NN && gt < NN + HF) S[gt - NN] = 0.f;
    grid.sync();

    // ---------------- phase 1: scatter (1 edge / thread) ----------------
    {
        int s = src[gt], d = dst[gt];
        int pos = atomicAdd(&cnt[s], 1);
        csr_dst[(s << 7) + pos] = d;
    }
    grid.sync();

    // ---------------- phase 2: GEMM tile + fused epilogues ----------------
    {
        __shared__ float As[TK][TM + 4];
        __shared__ float Bs[TK][TN + 4];
        __shared__ float Scol[TN];
        int tx = t & 15;
        int ty = t >> 4;
        int m0 = (b >> 3) * TM;     // 64 m-tiles
        int n0 = (b & 7) * TN;      // 8 n-tiles
        float acc[4][4] = {};

        float4 pa[2], pb[2];
#pragma unroll
        for (int i = 0; i < 2; ++i) {
            int flat = i * 256 + t, row = flat >> 3, c4 = flat & 7;
            pa[i] = *(const float4*)(x + (size_t)(m0 + row) * IN_F + c4 * 4);
        }
#pragma unroll
        for (int i = 0; i < 2; ++i) {
            int flat = i * 256 + t, row = flat >> 4, c4 = flat & 15;
            pb[i] = *(const float4*)(W + (size_t)row * HF + n0 + c4 * 4);
        }

        for (int k0 = 0; k0 < IN_F; k0 += TK) {
#pragma unroll
            for (int i = 0; i < 2; ++i) {
                int flat = i * 256 + t, row = flat >> 3, c4 = flat & 7;
                As[c4 * 4 + 0][row] = pa[i].x;
                As[c4 * 4 + 1][row] = pa[i].y;
                As[c4 * 4 + 2][row] = pa[i].z;
                As[c4 * 4 + 3][row] = pa[i].w;
            }
#pragma unroll
            for (int i = 0; i < 2; ++i) {
                int flat = i * 256 + t, row = flat >> 4, c4 = flat & 15;
                *(float4*)(&Bs[row][c4 * 4]) = pb[i];
            }
            __syncthreads();
            if (k0 + TK < IN_F) {
                int kn = k0 + TK;
#pragma unroll
                for (int i = 0; i < 2; ++i) {
                    int flat = i * 256 + t, row = flat >> 3, c4 = flat & 7;
                    pa[i] = *(const float4*)(x + (size_t)(m0 + row) * IN_F + kn + c4 * 4);
                }
#pragma unroll
                for (int i = 0; i < 2; ++i) {
                    int flat = i * 256 + t, row = flat >> 4, c4 = flat & 15;
                    pb[i] = *(const float4*)(W + (size_t)(kn + row) * HF + n0 + c4 * 4);
                }
            }
#pragma unroll
            for (int k = 0; k < TK; ++k) {
                float4 a4 = *(const float4*)(&As[k][ty * 4]);
                float4 b4 = *(const float4*)(&Bs[k][tx * 4]);
                float av[4] = {a4.x, a4.y, a4.z, a4.w};
                float bv[4] = {b4.x, b4.y, b4.z, b4.w};
#pragma unroll
                for (int ii = 0; ii < 4; ++ii)
#pragma unroll
                    for (int jj = 0; jj < 4; ++jj)
                        acc[ii][jj] += av[ii] * bv[jj];
            }
            __syncthreads();
        }

#pragma unroll
        for (int ii = 0; ii < 4; ++ii) {
            ushort4 v;
            v.x = f2b(acc[ii][0]);
            v.y = f2b(acc[ii][1]);
            v.z = f2b(acc[ii][2]);
            v.w = f2b(acc[ii][3]);
            *(ushort4*)(Whb + (size_t)(m0 + ty * 4 + ii) * HF + n0 + tx * 4) = v;
        }

        // alpha epilogue (fp32-exact): tile covers head h fully
        int h = n0 >> 6;
        float a1v[4], a2v[4];
#pragma unroll
        for (int jj = 0; jj < 4; ++jj) {
            int f = tx * 4 + jj;
            a1v[jj] = a[f];
            a2v[jj] = a[OUT_F + f];
        }
#pragma unroll
        for (int ii = 0; ii < 4; ++ii) {
            float p1 = 0.f, p2 = 0.f;
#pragma unroll
            for (int jj = 0; jj < 4; ++jj) {
                p1 += acc[ii][jj] * a1v[jj];
                p2 += acc[ii][jj] * a2v[jj];
            }
#pragma unroll
            for (int mask = 1; mask < 16; mask <<= 1) {
                p1 += __shfl_xor(p1, mask);
                p2 += __shfl_xor(p2, mask);
            }
            if (tx == 0) {
                int node = m0 + ty * 4 + ii;
                asrc[node * HH + h] = p1;
                adst[node * HH + h] = p2;
            }
        }

        // column-sum epilogue (fp32-exact)
        if (t < TN) Scol[t] = 0.f;
        __syncthreads();
#pragma unroll
        for (int jj = 0; jj < 4; ++jj) {
            float cs = acc[0][jj] + acc[1][jj] + acc[2][jj] + acc[3][jj];
            atomicAdd(&Scol[tx * 4 + jj], cs);
        }
        __syncthreads();
        if (t < TN) atomicAdd(&S[n0 + t], Scol[t]);
    }
    grid.sync();

    // ---------------- phase 3: aggregation (8 nodes / block) ----------------
    {
        __shared__ int           midx[CAP];
        __shared__ unsigned char dupf[CAP];
        __shared__ float         wbuf[CAP * HH];   // 4 KB
        __shared__ float         as_sh[HH];
        __shared__ float         denom[HH];
        __shared__ float         red[4][HF];       // 8 KB

        for (int i = b; i < NN; i += GRID) {
            int deg = cnt[i];
            if (deg > CAP) deg = CAP;

            if (t < HH) as_sh[t] = asrc[i * HH + t];
            for (int j = t; j < deg; j += BLK) midx[j] = csr_dst[(i << 7) + j];
            __syncthreads();

            // duplicate scan
            for (int j = t; j < deg; j += BLK) {
                int m = midx[j];
                unsigned char f = 0;
                for (int k = 0; k < j; ++k)
                    if (midx[k] == m) { f = 1; break; }
                dupf[j] = f;
            }
            __syncthreads();

            // staged parallel weights: thread per (slot, head)
            for (int idx = t; idx < deg * HH; idx += BLK) {
                int sl = idx >> 3, h = idx & 7;
                float w = 0.f;
                if (!dupf[sl]) {
                    float xv = as_sh[h] + adst[midx[sl] * HH + h];
                    xv = (xv > 0.f) ? xv : 0.2f * xv;
                    w = __expf(xv) - 1.f;
                }
                wbuf[idx] = w;
            }
            __syncthreads();

            // per-head denominators
            if (t < 128) {
                int h = t >> 4, ln = t & 15;
                float p = 0.f;
                for (int sl = ln; sl < deg; sl += 16) p += wbuf[sl * HH + h];
#pragma unroll
                for (int mask = 1; mask < 16; mask <<= 1) p += __shfl_xor(p, mask);
                if (ln == 0) denom[h] = (float)NN + p;
            }
            __syncthreads();

            // main gather: 4 groups x 64 lanes, 16B/lane, 1-deep pipeline
            int g = t >> 6;
            int r = t & 63;
            int h = r >> 3;
            float accv[8] = {};

            int j = g;
            uint4 uC = {0, 0, 0, 0};
            float wC = 0.f;
            if (j < deg) {
                wC = wbuf[j * HH + h];
                uC = *(const uint4*)(Whb + ((size_t)midx[j] << 9) + (r << 3));
            }
            while (j < deg) {
                int jn = j + 4;
                uint4 uN = {0, 0, 0, 0};
                float wN = 0.f;
                if (jn < deg) {
                    wN = wbuf[jn * HH + h];
                    uN = *(const uint4*)(Whb + ((size_t)midx[jn] << 9) + (r << 3));
                }
                accv[0] += wC * b2f(uC.x & 0xFFFFu);
                accv[1] += wC * b2f(uC.x >> 16);
                accv[2] += wC * b2f(uC.y & 0xFFFFu);
                accv[3] += wC * b2f(uC.y >> 16);
                accv[4] += wC * b2f(uC.z & 0xFFFFu);
                accv[5] += wC * b2f(uC.z >> 16);
                accv[6] += wC * b2f(uC.w & 0xFFFFu);
                accv[7] += wC * b2f(uC.w >> 16);
                uC = uN; wC = wN; j = jn;
            }

            float4 v0 = {accv[0], accv[1], accv[2], accv[3]};
            float4 v1 = {accv[4], accv[5], accv[6], accv[7]};
            *(float4*)(&red[g][r * 8])     = v0;
            *(float4*)(&red[g][r * 8 + 4]) = v1;
            __syncthreads();

            for (int o = t; o < HF; o += BLK) {
                float tot = S[o] + red[0][o] + red[1][o] + red[2][o] + red[3][o];
                out[((size_t)i << 9) + o] = tot / denom[o >> 6];
            }
            __syncthreads();   // protect LDS reuse for next node
        }
    }
}

// ---------------------------------------------------------------------------
// launcher
// ---------------------------------------------------------------------------
extern "C" void kernel_launch(void* const* d_in, const int* in_sizes, int n_in,
                              void* d_out, int out_size, void* d_ws, size_t ws_size,
                              hipStream_t stream) {
    const float* x  = (const float*)d_in[0];
    const float* W  = (const float*)d_in[1];
    const float* a  = (const float*)d_in[2];
    const int*   ei = (const int*)d_in[3];
    const int* src = ei;
    const int* dst = ei + EE;
    float* out = (float*)d_out;

    // workspace layout (bytes)
    char* ws = (char*)d_ws;
    unsigned short* Whb = (unsigned short*)(ws + 0);   // 4,194,304
    float* asrc     = (float*)(ws + 4194304);          // 131,072
    float* adst     = (float*)(ws + 4325376);          // 131,072
    int*   csr_dst  = (int*)  (ws + 4456448);          // 2,097,152
    float* S        = (float*)(ws + 6553600);          // 2,048
    int*   cnt      = (int*)  (ws + 6555648);          // 16,384

    void* args[] = {(void*)&x, (void*)&W, (void*)&a, (void*)&src, (void*)&dst,
                    (void*)&Whb, (void*)&asrc, (void*)&adst, (void*)&S,
                    (void*)&cnt, (void*)&csr_dst, (void*)&out};
    hipLaunchCooperativeKernel((const void*)gat_mega, dim3(GRID), dim3(BLK),
                               args, 0, stream);
}

// Round 9
// 128.281 us; speedup vs baseline: 2.4975x; 2.4975x over previous
//
#include <hip/hip_runtime.h>
#include <hip/hip_bf16.h>

// Problem constants
constexpr int NN    = 4096;     // nodes
constexpr int EE    = 131072;   // edges
constexpr int IN_F  = 256;
constexpr int OUT_F = 64;
constexpr int HH    = 8;
constexpr int HF    = OUT_F * HH;   // 512
constexpr int CAP   = 128;          // CSR capacity (raw deg: mean 32, 17-sigma < 128)

// f32 -> bf16 round-to-nearest-even
__device__ __forceinline__ unsigned short f2b(float f) {
    unsigned int u = __float_as_uint(f);
    u = u + 0x7FFFu + ((u >> 16) & 1u);
    return (unsigned short)(u >> 16);
}
// bf16 (as u16) -> f32 (exact)
__device__ __forceinline__ float b2f(unsigned int lo16) {
    return __uint_as_float(lo16 << 16);
}

#define TM 64
#define TN 64
#define TK 32

// ---------------------------------------------------------------------------
// K1: scatter prologue + double-buffered GEMM + fused epilogues.
// 512 blocks x 256 threads. Block b: edges [b*256, b*256+256) then GEMM tile
// (m0,n0) = ((b>>3)*64, (b&7)*64). Double-buffered LDS: ONE barrier per
// K-step; next tile's global loads in flight during compute.
// ---------------------------------------------------------------------------
__global__ __launch_bounds__(256) void gemm_scatter(const float* __restrict__ x,
                                                    const float* __restrict__ W,
                                                    const float* __restrict__ a,
                                                    const int* __restrict__ src,
                                                    const int* __restrict__ dst,
                                                    int* __restrict__ cnt,
                                                    int* __restrict__ csr_dst,
                                                    unsigned short* __restrict__ Whb,
                                                    float* __restrict__ asrc,
                                                    float* __restrict__ adst,
                                                    float* __restrict__ S) {
    __shared__ float As[2][TK][TM + 4];   // 2 x 32 x 68
    __shared__ float Bs[2][TK][TN + 4];
    __shared__ float Scol[TN];
    int b = blockIdx.x;
    int t = threadIdx.x;

    // ---- scatter prologue: 1 edge / thread (atomics retire under GEMM) ----
    {
        int e = b * 256 + t;
        int s = src[e], d = dst[e];
        int pos = atomicAdd(&cnt[s], 1);
        csr_dst[(s << 7) + pos] = d;
    }

    // ---- GEMM ----
    int tx = t & 15;
    int ty = t >> 4;
    int m0 = (b >> 3) * TM;
    int n0 = (b & 7) * TN;
    float acc[4][4] = {};
    float4 pa[2], pb[2];

    // load tile 0 into regs
#pragma unroll
    for (int i = 0; i < 2; ++i) {
        int flat = i * 256 + t, row = flat >> 3, c4 = flat & 7;
        pa[i] = *(const float4*)(x + (size_t)(m0 + row) * IN_F + c4 * 4);
    }
#pragma unroll
    for (int i = 0; i < 2; ++i) {
        int flat = i * 256 + t, row = flat >> 4, c4 = flat & 15;
        pb[i] = *(const float4*)(W + (size_t)row * HF + n0 + c4 * 4);
    }
    // store tile 0 into buf 0
#pragma unroll
    for (int i = 0; i < 2; ++i) {
        int flat = i * 256 + t, row = flat >> 3, c4 = flat & 7;
        As[0][c4 * 4 + 0][row] = pa[i].x;
        As[0][c4 * 4 + 1][row] = pa[i].y;
        As[0][c4 * 4 + 2][row] = pa[i].z;
        As[0][c4 * 4 + 3][row] = pa[i].w;
    }
#pragma unroll
    for (int i = 0; i < 2; ++i) {
        int flat = i * 256 + t, row = flat >> 4, c4 = flat & 15;
        *(float4*)(&Bs[0][row][c4 * 4]) = pb[i];
    }
    __syncthreads();

    for (int s8 = 0; s8 < 8; ++s8) {
        int cur = s8 & 1;
        if (s8 < 7) {
            int kn = (s8 + 1) * TK;
#pragma unroll
            for (int i = 0; i < 2; ++i) {
                int flat = i * 256 + t, row = flat >> 3, c4 = flat & 7;
                pa[i] = *(const float4*)(x + (size_t)(m0 + row) * IN_F + kn + c4 * 4);
            }
#pragma unroll
            for (int i = 0; i < 2; ++i) {
                int flat = i * 256 + t, row = flat >> 4, c4 = flat & 15;
                pb[i] = *(const float4*)(W + (size_t)(kn + row) * HF + n0 + c4 * 4);
            }
        }
#pragma unroll
        for (int k = 0; k < TK; ++k) {
            float4 a4 = *(const float4*)(&As[cur][k][ty * 4]);
            float4 b4 = *(const float4*)(&Bs[cur][k][tx * 4]);
            float av[4] = {a4.x, a4.y, a4.z, a4.w};
            float bv[4] = {b4.x, b4.y, b4.z, b4.w};
#pragma unroll
            for (int ii = 0; ii < 4; ++ii)
#pragma unroll
                for (int jj = 0; jj < 4; ++jj)
                    acc[ii][jj] += av[ii] * bv[jj];
        }
        if (s8 < 7) {
            int nxt = cur ^ 1;
            // store into the OTHER buffer: no barrier needed before (different
            // buffer than the one being read); one barrier after.
#pragma unroll
            for (int i = 0; i < 2; ++i) {
                int flat = i * 256 + t, row = flat >> 3, c4 = flat & 7;
                As[nxt][c4 * 4 + 0][row] = pa[i].x;
                As[nxt][c4 * 4 + 1][row] = pa[i].y;
                As[nxt][c4 * 4 + 2][row] = pa[i].z;
                As[nxt][c4 * 4 + 3][row] = pa[i].w;
            }
#pragma unroll
            for (int i = 0; i < 2; ++i) {
                int flat = i * 256 + t, row = flat >> 4, c4 = flat & 15;
                *(float4*)(&Bs[nxt][row][c4 * 4]) = pb[i];
            }
            __syncthreads();
        }
    }

    // ---- Whb store (bf16) ----
#pragma unroll
    for (int ii = 0; ii < 4; ++ii) {
        ushort4 v;
        v.x = f2b(acc[ii][0]);
        v.y = f2b(acc[ii][1]);
        v.z = f2b(acc[ii][2]);
        v.w = f2b(acc[ii][3]);
        *(ushort4*)(Whb + (size_t)(m0 + ty * 4 + ii) * HF + n0 + tx * 4) = v;
    }

    // ---- alpha epilogue (fp32-exact): tile covers head h fully ----
    int h = n0 >> 6;
    float a1v[4], a2v[4];
#pragma unroll
    for (int jj = 0; jj < 4; ++jj) {
        int f = tx * 4 + jj;
        a1v[jj] = a[f];
        a2v[jj] = a[OUT_F + f];
    }
#pragma unroll
    for (int ii = 0; ii < 4; ++ii) {
        float p1 = 0.f, p2 = 0.f;
#pragma unroll
        for (int jj = 0; jj < 4; ++jj) {
            p1 += acc[ii][jj] * a1v[jj];
            p2 += acc[ii][jj] * a2v[jj];
        }
#pragma unroll
        for (int mask = 1; mask < 16; mask <<= 1) {
            p1 += __shfl_xor(p1, mask);
            p2 += __shfl_xor(p2, mask);
        }
        if (tx == 0) {
            int node = m0 + ty * 4 + ii;
            asrc[node * HH + h] = p1;
            adst[node * HH + h] = p2;
        }
    }

    // ---- column-sum epilogue (fp32-exact) ----
    if (t < TN) Scol[t] = 0.f;
    __syncthreads();
#pragma unroll
    for (int jj = 0; jj < 4; ++jj) {
        float cs = acc[0][jj] + acc[1][jj] + acc[2][jj] + acc[3][jj];
        atomicAdd(&Scol[tx * 4 + jj], cs);
    }
    __syncthreads();
    if (t < TN) atomicAdd(&S[n0 + t], Scol[t]);
}

// ---------------------------------------------------------------------------
// K2: per-node aggregation with in-LDS dedup + staged weights (R6-proven).
// out[i,h,f] = (S[h,f] + sum_unique w*Whb[m,h,f]) / (N + sum_unique w)
// 4096 blocks x 512 thr = 8 groups x 64 lanes; lane reads uint4 (8 bf16).
// ---------------------------------------------------------------------------
__global__ __launch_bounds__(512) void aggregate_kernel(const unsigned short* __restrict__ Whb,
                                                        const float* __restrict__ asrc,
                                                        const float* __restrict__ adst,
                                                        const float* __restrict__ S,
                                                        const int* __restrict__ cnt,
                                                        const int* __restrict__ csr_dst,
                                                        float* __restrict__ out) {
    __shared__ int           midx[CAP];
    __shared__ unsigned char dupf[CAP];
    __shared__ float         wbuf[CAP * HH];   // 4 KB
    __shared__ float         as_sh[HH];
    __shared__ float         denom[HH];
    __shared__ float         red[8][HF];       // 16 KB
    int i = blockIdx.x;
    int t = threadIdx.x;                       // 0..511
    int deg = cnt[i];
    if (deg > CAP) deg = CAP;

    if (t < HH) as_sh[t] = asrc[i * HH + t];
    for (int j = t; j < deg; j += 512) midx[j] = csr_dst[(i << 7) + j];
    __syncthreads();

    // duplicate scan: slot j is dup iff an earlier slot holds the same index
    for (int j = t; j < deg; j += 512) {
        int m = midx[j];
        unsigned char f = 0;
        for (int k = 0; k < j; ++k)
            if (midx[k] == m) { f = 1; break; }
        dupf[j] = f;
    }
    __syncthreads();

    // staged parallel weights: thread per (slot, head)
    for (int idx = t; idx < deg * HH; idx += 512) {
        int sl = idx >> 3, h = idx & 7;
        float w = 0.f;
        if (!dupf[sl]) {
            float xv = as_sh[h] + adst[midx[sl] * HH + h];
            xv = (xv > 0.f) ? xv : 0.2f * xv;      // leaky_relu(., 0.2)
            w = __expf(xv) - 1.f;
        }
        wbuf[idx] = w;
    }
    __syncthreads();

    // per-head denominators
    if (t < 128) {
        int h = t >> 4, ln = t & 15;
        float p = 0.f;
        for (int sl = ln; sl < deg; sl += 16) p += wbuf[sl * HH + h];
#pragma unroll
        for (int mask = 1; mask < 16; mask <<= 1) p += __shfl_xor(p, mask);
        if (ln == 0) denom[h] = (float)NN + p;
    }
    __syncthreads();

    // main gather: 8 groups x 64 lanes, 16B/lane, 1-deep pipeline
    int g = t >> 6;
    int r = t & 63;
    int h = r >> 3;
    float accv[8] = {};

    int j = g;
    uint4 uC = {0, 0, 0, 0};
    float wC = 0.f;
    if (j < deg) {
        wC = wbuf[j * HH + h];
        uC = *(const uint4*)(Whb + ((size_t)midx[j] << 9) + (r << 3));
    }
    while (j < deg) {
        int jn = j + 8;
        uint4 uN = {0, 0, 0, 0};
        float wN = 0.f;
        if (jn < deg) {
            wN = wbuf[jn * HH + h];
            uN = *(const uint4*)(Whb + ((size_t)midx[jn] << 9) + (r << 3));
        }
        accv[0] += wC * b2f(uC.x & 0xFFFFu);
        accv[1] += wC * b2f(uC.x >> 16);
        accv[2] += wC * b2f(uC.y & 0xFFFFu);
        accv[3] += wC * b2f(uC.y >> 16);
        accv[4] += wC * b2f(uC.z & 0xFFFFu);
        accv[5] += wC * b2f(uC.z >> 16);
        accv[6] += wC * b2f(uC.w & 0xFFFFu);
        accv[7] += wC * b2f(uC.w >> 16);
        uC = uN; wC = wN; j = jn;
    }

    float4 v0 = {accv[0], accv[1], accv[2], accv[3]};
    float4 v1 = {accv[4], accv[5], accv[6], accv[7]};
    *(float4*)(&red[g][r * 8])     = v0;
    *(float4*)(&red[g][r * 8 + 4]) = v1;
    __syncthreads();

    float tot = S[t];
#pragma unroll
    for (int gg = 0; gg < 8; ++gg) tot += red[gg][t];
    out[((size_t)i << 9) + t] = tot / denom[t >> 6];
}

// ---------------------------------------------------------------------------
// launcher: 3 dispatches (memset, gemm+scatter, aggregate)
// ---------------------------------------------------------------------------
extern "C" void kernel_launch(void* const* d_in, const int* in_sizes, int n_in,
                              void* d_out, int out_size, void* d_ws, size_t ws_size,
                              hipStream_t stream) {
    const float* x  = (const float*)d_in[0];
    const float* W  = (const float*)d_in[1];
    const float* a  = (const float*)d_in[2];
    const int*   ei = (const int*)d_in[3];
    const int* src = ei;
    const int* dst = ei + EE;
    float* out = (float*)d_out;

    // workspace layout (bytes)
    char* ws = (char*)d_ws;
    unsigned short* Whb = (unsigned short*)(ws + 0);   // 4,194,304
    float* asrc     = (float*)(ws + 4194304);          // 131,072
    float* adst     = (float*)(ws + 4325376);          // 131,072
    int*   csr_dst  = (int*)  (ws + 4456448);          // 2,097,152
    float* S        = (float*)(ws + 6553600);          // 2,048
    int*   cnt      = (int*)  (ws + 6555648);          // 16,384

    // zero S + cnt (contiguous, 18.4 KB)
    hipMemsetAsync(ws + 6553600, 0, 2048 + 16384, stream);

    // K1: scatter + GEMM (bf16 Wh out) + alphas + column sums
    gemm_scatter<<<512, 256, 0, stream>>>(x, W, a, src, dst, cnt, csr_dst,
                                          Whb, asrc, adst, S);

    // K2: aggregation (dedup + weights + gather)
    aggregate_kernel<<<NN, 512, 0, stream>>>(Whb, asrc, adst, S, cnt, csr_dst, out);
}

// Round 10
// 119.108 us; speedup vs baseline: 2.6899x; 1.0770x over previous
//
#include <hip/hip_runtime.h>
#include <hip/hip_bf16.h>

// Problem constants
constexpr int NN    = 4096;     // nodes
constexpr int EE    = 131072;   // edges
constexpr int IN_F  = 256;
constexpr int OUT_F = 64;
constexpr int HH    = 8;
constexpr int HF    = OUT_F * HH;   // 512
constexpr int CAP   = 128;          // CSR capacity (raw deg: mean 32, 17-sigma < 128)

typedef __attribute__((ext_vector_type(8))) short bf16x8;   // MFMA A/B frag
typedef __attribute__((ext_vector_type(4))) float f32x4;    // MFMA C/D frag

// f32 -> bf16 round-to-nearest-even
__device__ __forceinline__ unsigned short f2b(float f) {
    unsigned int u = __float_as_uint(f);
    u = u + 0x7FFFu + ((u >> 16) & 1u);
    return (unsigned short)(u >> 16);
}
// bf16 (as u16) -> f32 (exact)
__device__ __forceinline__ float b2f(unsigned int lo16) {
    return __uint_as_float(lo16 << 16);
}

// ---------------------------------------------------------------------------
// K0: preconvert x -> (xhi,xlo) bf16; W -> WT (transposed) hi/lo bf16;
//     zero cnt + S.  576 blocks x 256 threads.
//     blocks 0..511: x (8 elems/thread).  blocks 512..575: W transpose + zero.
// ---------------------------------------------------------------------------
__global__ __launch_bounds__(256) void preconvert(const float* __restrict__ x,
                                                  const float* __restrict__ W,
                                                  unsigned short* __restrict__ xhi,
                                                  unsigned short* __restrict__ xlo,
                                                  unsigned short* __restrict__ WThi,
                                                  unsigned short* __restrict__ WTlo,
                                                  float* __restrict__ S,
                                                  int* __restrict__ cnt) {
    int b = blockIdx.x, t = threadIdx.x;
    if (b < 512) {
        int base = (b * 256 + t) * 8;
        float4 v0 = *(const float4*)(x + base);
        float4 v1 = *(const float4*)(x + base + 4);
        float f[8] = {v0.x, v0.y, v0.z, v0.w, v1.x, v1.y, v1.z, v1.w};
        unsigned short hi[8], lo[8];
#pragma unroll
        for (int j = 0; j < 8; ++j) {
            hi[j] = f2b(f[j]);
            lo[j] = f2b(f[j] - b2f(hi[j]));
        }
        *(ushort4*)(xhi + base)     = make_ushort4(hi[0], hi[1], hi[2], hi[3]);
        *(ushort4*)(xhi + base + 4) = make_ushort4(hi[4], hi[5], hi[6], hi[7]);
        *(ushort4*)(xlo + base)     = make_ushort4(lo[0], lo[1], lo[2], lo[3]);
        *(ushort4*)(xlo + base + 4) = make_ushort4(lo[4], lo[5], lo[6], lo[7]);
    } else {
        int bb = b - 512;
        int gt2 = bb * 256 + t;
        if (gt2 < NN) cnt[gt2] = 0;
        else if (gt2 < NN + HF) S[gt2 - NN] = 0.f;
        // W transpose: thread -> (n, kbase): 8 consecutive k at fixed n
        int n  = bb * 8 + (t >> 5);
        int kb = (t & 31) * 8;
        unsigned short hi[8], lo[8];
#pragma unroll
        for (int j = 0; j < 8; ++j) {
            float f = W[(size_t)(kb + j) * HF + n];
            hi[j] = f2b(f);
            lo[j] = f2b(f - b2f(hi[j]));
        }
        size_t o = (size_t)n * 256 + kb;
        *(ushort4*)(WThi + o)     = make_ushort4(hi[0], hi[1], hi[2], hi[3]);
        *(ushort4*)(WThi + o + 4) = make_ushort4(hi[4], hi[5], hi[6], hi[7]);
        *(ushort4*)(WTlo + o)     = make_ushort4(lo[0], lo[1], lo[2], lo[3]);
        *(ushort4*)(WTlo + o + 4) = make_ushort4(lo[4], lo[5], lo[6], lo[7]);
    }
}

// ---------------------------------------------------------------------------
// K1: scatter prologue + MFMA GEMM (split-bf16, 3 passes) + fused epilogues.
// 512 blocks x 256 thr (4 waves). Block b: tile (m0,n0)=((b>>3)*64,(b&7)*64).
// Wave w owns rows m0+w*16..+15, all 64 cols (4 x 16x16 tiles).
// B (= W^T tile, all K) staged ONCE in padded LDS -> no barriers in K-loop.
// A-frags read straight from global xhi/xlo (16B/lane, L2-resident rereads).
// acc = xhi*Whi + xhi*Wlo + xlo*Whi  (~1e-5 rel error, fp32-equivalent here).
// ---------------------------------------------------------------------------
__global__ __launch_bounds__(256) void gemm_mfma(const unsigned short* __restrict__ xhi,
                                                 const unsigned short* __restrict__ xlo,
                                                 const unsigned short* __restrict__ WThi,
                                                 const unsigned short* __restrict__ WTlo,
                                                 const float* __restrict__ a,
                                                 const int* __restrict__ src,
                                                 const int* __restrict__ dst,
                                                 int* __restrict__ cnt,
                                                 int* __restrict__ csr_dst,
                                                 unsigned short* __restrict__ Whb,
                                                 float* __restrict__ asrc,
                                                 float* __restrict__ adst,
                                                 float* __restrict__ S) {
    __shared__ unsigned short Bhi_s[64][264];   // +8 pad: b128 reads ~conflict-free
    __shared__ unsigned short Blo_s[64][264];
    __shared__ float Scol[64];
    int b = blockIdx.x;
    int t = threadIdx.x;

    // ---- scatter prologue: 1 edge / thread (atomics retire under GEMM) ----
    {
        int e = b * 256 + t;
        int s = src[e], d = dst[e];
        int pos = atomicAdd(&cnt[s], 1);
        csr_dst[(s << 7) + pos] = d;
    }

    int m0 = (b >> 3) * 64;
    int n0 = (b & 7) * 64;
    if (t < 64) Scol[t] = 0.f;

    // ---- stage B tile (n0..n0+63, all 256 K) hi+lo into LDS ----
#pragma unroll
    for (int it = 0; it < 8; ++it) {
        int flat = it * 256 + t;       // 0..2047 dwordx4-units (32 per row)
        int row  = flat >> 5;
        int cu   = flat & 31;
        *(uint4*)(&Bhi_s[row][cu * 8]) =
            *(const uint4*)(WThi + (size_t)(n0 + row) * 256 + cu * 8);
        *(uint4*)(&Blo_s[row][cu * 8]) =
            *(const uint4*)(WTlo + (size_t)(n0 + row) * 256 + cu * 8);
    }
    __syncthreads();

    // ---- MFMA K-loop (no barriers) ----
    int w  = t >> 6;       // wave 0..3 -> rows m0+w*16..+15
    int l  = t & 63;
    int kg = l >> 4;       // k-group 0..3
    int ln = l & 15;
    int arow = m0 + w * 16 + ln;

    f32x4 acc[4] = {};     // 4 n-tiles

#pragma unroll
    for (int ks = 0; ks < 8; ++ks) {
        size_t aoff = (size_t)arow * 256 + ks * 32 + kg * 8;
        bf16x8 ahi = *(const bf16x8*)(xhi + aoff);
        bf16x8 alo = *(const bf16x8*)(xlo + aoff);
#pragma unroll
        for (int nt = 0; nt < 4; ++nt) {
            const unsigned short* bp = &Bhi_s[nt * 16 + ln][ks * 32 + kg * 8];
            const unsigned short* lp = &Blo_s[nt * 16 + ln][ks * 32 + kg * 8];
            bf16x8 bhi = *(const bf16x8*)bp;
            bf16x8 blo = *(const bf16x8*)lp;
            acc[nt] = __builtin_amdgcn_mfma_f32_16x16x32_bf16(ahi, bhi, acc[nt], 0, 0, 0);
            acc[nt] = __builtin_amdgcn_mfma_f32_16x16x32_bf16(ahi, blo, acc[nt], 0, 0, 0);
            acc[nt] = __builtin_amdgcn_mfma_f32_16x16x32_bf16(alo, bhi, acc[nt], 0, 0, 0);
        }
    }

    // ---- Whb store (bf16). C/D layout: col=ln, row=kg*4+i ----
#pragma unroll
    for (int nt = 0; nt < 4; ++nt)
#pragma unroll
        for (int i = 0; i < 4; ++i) {
            int row = m0 + w * 16 + kg * 4 + i;
            Whb[(size_t)row * HF + n0 + nt * 16 + ln] = f2b(acc[nt][i]);
        }

    // ---- alpha epilogue (fp32-exact): tile covers head h fully ----
    int h = n0 >> 6;
    float a1v[4], a2v[4];
#pragma unroll
    for (int nt = 0; nt < 4; ++nt) {
        a1v[nt] = a[nt * 16 + ln];
        a2v[nt] = a[OUT_F + nt * 16 + ln];
    }
#pragma unroll
    for (int i = 0; i < 4; ++i) {
        float p1 = acc[0][i] * a1v[0] + acc[1][i] * a1v[1] +
                   acc[2][i] * a1v[2] + acc[3][i] * a1v[3];
        float p2 = acc[0][i] * a2v[0] + acc[1][i] * a2v[1] +
                   acc[2][i] * a2v[2] + acc[3][i] * a2v[3];
#pragma unroll
        for (int mask = 1; mask < 16; mask <<= 1) {   // reduce over ln (cols)
            p1 += __shfl_xor(p1, mask);
            p2 += __shfl_xor(p2, mask);
        }
        if (ln == 0) {
            int node = m0 + w * 16 + kg * 4 + i;
            asrc[node * HH + h] = p1;
            adst[node * HH + h] = p2;
        }
    }

    // ---- column-sum epilogue ----
#pragma unroll
    for (int nt = 0; nt < 4; ++nt) {
        float cs = acc[nt][0] + acc[nt][1] + acc[nt][2] + acc[nt][3];
        cs += __shfl_xor(cs, 16);   // reduce over kg (rows)
        cs += __shfl_xor(cs, 32);
        if (kg == 0) atomicAdd(&Scol[nt * 16 + ln], cs);
    }
    __syncthreads();
    if (t < 64) atomicAdd(&S[n0 + t], Scol[t]);
}

// ---------------------------------------------------------------------------
// K2: per-node aggregation with in-LDS dedup + staged weights (R9-proven).
// out[i,h,f] = (S[h,f] + sum_unique w*Whb[m,h,f]) / (N + sum_unique w)
// 4096 blocks x 512 thr = 8 groups x 64 lanes; lane reads uint4 (8 bf16).
// ---------------------------------------------------------------------------
__global__ __launch_bounds__(512) void aggregate_kernel(const unsigned short* __restrict__ Whb,
                                                        const float* __restrict__ asrc,
                                                        const float* __restrict__ adst,
                                                        const float* __restrict__ S,
                                                        const int* __restrict__ cnt,
                                                        const int* __restrict__ csr_dst,
                                                        float* __restrict__ out) {
    __shared__ int           midx[CAP];
    __shared__ unsigned char dupf[CAP];
    __shared__ float         wbuf[CAP * HH];   // 4 KB
    __shared__ float         as_sh[HH];
    __shared__ float         denom[HH];
    __shared__ float         red[8][HF];       // 16 KB
    int i = blockIdx.x;
    int t = threadIdx.x;                       // 0..511
    int deg = cnt[i];
    if (deg > CAP) deg = CAP;

    if (t < HH) as_sh[t] = asrc[i * HH + t];
    for (int j = t; j < deg; j += 512) midx[j] = csr_dst[(i << 7) + j];
    __syncthreads();

    // duplicate scan: slot j is dup iff an earlier slot holds the same index
    for (int j = t; j < deg; j += 512) {
        int m = midx[j];
        unsigned char f = 0;
        for (int k = 0; k < j; ++k)
            if (midx[k] == m) { f = 1; break; }
        dupf[j] = f;
    }
    __syncthreads();

    // staged parallel weights: thread per (slot, head)
    for (int idx = t; idx < deg * HH; idx += 512) {
        int sl = idx >> 3, h = idx & 7;
        float w = 0.f;
        if (!dupf[sl]) {
            float xv = as_sh[h] + adst[midx[sl] * HH + h];
            xv = (xv > 0.f) ? xv : 0.2f * xv;      // leaky_relu(., 0.2)
            w = __expf(xv) - 1.f;
        }
        wbuf[idx] = w;
    }
    __syncthreads();

    // per-head denominators
    if (t < 128) {
        int h = t >> 4, ln = t & 15;
        float p = 0.f;
        for (int sl = ln; sl < deg; sl += 16) p += wbuf[sl * HH + h];
#pragma unroll
        for (int mask = 1; mask < 16; mask <<= 1) p += __shfl_xor(p, mask);
        if (ln == 0) denom[h] = (float)NN + p;
    }
    __syncthreads();

    // main gather: 8 groups x 64 lanes, 16B/lane, 1-deep pipeline
    int g = t >> 6;
    int r = t & 63;
    int h = r >> 3;
    float accv[8] = {};

    int j = g;
    uint4 uC = {0, 0, 0, 0};
    float wC = 0.f;
    if (j < deg) {
        wC = wbuf[j * HH + h];
        uC = *(const uint4*)(Whb + ((size_t)midx[j] << 9) + (r << 3));
    }
    while (j < deg) {
        int jn = j + 8;
        uint4 uN = {0, 0, 0, 0};
        float wN = 0.f;
        if (jn < deg) {
            wN = wbuf[jn * HH + h];
            uN = *(const uint4*)(Whb + ((size_t)midx[jn] << 9) + (r << 3));
        }
        accv[0] += wC * b2f(uC.x & 0xFFFFu);
        accv[1] += wC * b2f(uC.x >> 16);
        accv[2] += wC * b2f(uC.y & 0xFFFFu);
        accv[3] += wC * b2f(uC.y >> 16);
        accv[4] += wC * b2f(uC.z & 0xFFFFu);
        accv[5] += wC * b2f(uC.z >> 16);
        accv[6] += wC * b2f(uC.w & 0xFFFFu);
        accv[7] += wC * b2f(uC.w >> 16);
        uC = uN; wC = wN; j = jn;
    }

    float4 v0 = {accv[0], accv[1], accv[2], accv[3]};
    float4 v1 = {accv[4], accv[5], accv[6], accv[7]};
    *(float4*)(&red[g][r * 8])     = v0;
    *(float4*)(&red[g][r * 8 + 4]) = v1;
    __syncthreads();

    float tot = S[t];
#pragma unroll
    for (int gg = 0; gg < 8; ++gg) tot += red[gg][t];
    out[((size_t)i << 9) + t] = tot / denom[t >> 6];
}

// ---------------------------------------------------------------------------
// launcher: 3 dispatches (preconvert+zero, gemm+scatter, aggregate)
// ---------------------------------------------------------------------------
extern "C" void kernel_launch(void* const* d_in, const int* in_sizes, int n_in,
                              void* d_out, int out_size, void* d_ws, size_t ws_size,
                              hipStream_t stream) {
    const float* x  = (const float*)d_in[0];
    const float* W  = (const float*)d_in[1];
    const float* a  = (const float*)d_in[2];
    const int*   ei = (const int*)d_in[3];
    const int* src = ei;
    const int* dst = ei + EE;
    float* out = (float*)d_out;

    // workspace layout (bytes)
    char* ws = (char*)d_ws;
    unsigned short* Whb  = (unsigned short*)(ws + 0);          // 4,194,304
    unsigned short* xhi  = (unsigned short*)(ws + 4194304);    // 2,097,152
    unsigned short* xlo  = (unsigned short*)(ws + 6291456);    // 2,097,152
    unsigned short* WThi = (unsigned short*)(ws + 8388608);    // 262,144
    unsigned short* WTlo = (unsigned short*)(ws + 8650752);    // 262,144
    float* asrc     = (float*)(ws + 8912896);                  // 131,072
    float* adst     = (float*)(ws + 9043968);                  // 131,072
    int*   csr_dst  = (int*)  (ws + 9175040);                  // 2,097,152
    float* S        = (float*)(ws + 11272192);                 // 2,048
    int*   cnt      = (int*)  (ws + 11274240);                 // 16,384

    // K0: bf16 split conversion + W transpose + zero cnt/S
    preconvert<<<576, 256, 0, stream>>>(x, W, xhi, xlo, WThi, WTlo, S, cnt);

    // K1: scatter + MFMA GEMM + alphas + column sums
    gemm_mfma<<<512, 256, 0, stream>>>(xhi, xlo, WThi, WTlo, a, src, dst,
                                       cnt, csr_dst, Whb, asrc, adst, S);

    // K2: aggregation (dedup + weights + gather)
    aggregate_kernel<<<NN, 512, 0, stream>>>(Whb, asrc, adst, S, cnt, csr_dst, out);
}

// Round 11
// 118.271 us; speedup vs baseline: 2.7089x; 1.0071x over previous
//
#include <hip/hip_runtime.h>
#include <hip/hip_bf16.h>

// Problem constants
constexpr int NN    = 4096;     // nodes
constexpr int EE    = 131072;   // edges
constexpr int IN_F  = 256;
constexpr int OUT_F = 64;
constexpr int HH    = 8;
constexpr int HF    = OUT_F * HH;   // 512
constexpr int CAP   = 128;          // CSR capacity (raw deg: mean 32, 17-sigma < 128)

typedef __attribute__((ext_vector_type(8))) short bf16x8;   // MFMA A/B frag
typedef __attribute__((ext_vector_type(4))) float f32x4;    // MFMA C/D frag

// f32 -> bf16 round-to-nearest-even
__device__ __forceinline__ unsigned short f2b(float f) {
    unsigned int u = __float_as_uint(f);
    u = u + 0x7FFFu + ((u >> 16) & 1u);
    return (unsigned short)(u >> 16);
}
// bf16 (as u16) -> f32 (exact)
__device__ __forceinline__ float b2f(unsigned int lo16) {
    return __uint_as_float(lo16 << 16);
}

// ---------------------------------------------------------------------------
// K0: W -> WT (transposed) hi/lo bf16 split; zero cnt + S.
// 82 blocks x 256 threads. Blocks 0..63: W transpose. 64..81: zeroing.
// ---------------------------------------------------------------------------
__global__ __launch_bounds__(256) void prep(const float* __restrict__ W,
                                            unsigned short* __restrict__ WThi,
                                            unsigned short* __restrict__ WTlo,
                                            float* __restrict__ S,
                                            int* __restrict__ cnt) {
    int b = blockIdx.x, t = threadIdx.x;
    if (b < 64) {
        // thread -> (n, kbase): 8 consecutive k at fixed n
        int n  = b * 8 + (t >> 5);
        int kb = (t & 31) * 8;
        unsigned short hi[8], lo[8];
#pragma unroll
        for (int j = 0; j < 8; ++j) {
            float f = W[(size_t)(kb + j) * HF + n];
            hi[j] = f2b(f);
            lo[j] = f2b(f - b2f(hi[j]));
        }
        size_t o = (size_t)n * 256 + kb;
        *(ushort4*)(WThi + o)     = make_ushort4(hi[0], hi[1], hi[2], hi[3]);
        *(ushort4*)(WThi + o + 4) = make_ushort4(hi[4], hi[5], hi[6], hi[7]);
        *(ushort4*)(WTlo + o)     = make_ushort4(lo[0], lo[1], lo[2], lo[3]);
        *(ushort4*)(WTlo + o + 4) = make_ushort4(lo[4], lo[5], lo[6], lo[7]);
    } else {
        int gt = (b - 64) * 256 + t;
        if (gt < NN) cnt[gt] = 0;
        else if (gt < NN + HF) S[gt - NN] = 0.f;
    }
}

// ---------------------------------------------------------------------------
// K1: scatter prologue + MFMA GEMM (split-bf16, 3 passes) + fused epilogues.
// 512 blocks x 256 thr (4 waves). Block b: tile (m0,n0)=((b>>3)*64,(b&7)*64).
// B (= W^T tile, all K) staged ONCE in padded LDS -> no barriers in K-loop.
// A converted fp32->bf16 hi/lo ON THE FLY from x (32B/lane/K-step, L2-hot).
// acc = xhi*Whi + xhi*Wlo + xlo*Whi  (~1e-5 rel error, fp32-equivalent here).
// ---------------------------------------------------------------------------
__global__ __launch_bounds__(256) void gemm_mfma(const float* __restrict__ xf,
                                                 const unsigned short* __restrict__ WThi,
                                                 const unsigned short* __restrict__ WTlo,
                                                 const float* __restrict__ a,
                                                 const int* __restrict__ src,
                                                 const int* __restrict__ dst,
                                                 int* __restrict__ cnt,
                                                 int* __restrict__ csr_dst,
                                                 unsigned short* __restrict__ Whb,
                                                 float* __restrict__ asrc,
                                                 float* __restrict__ adst,
                                                 float* __restrict__ S) {
    __shared__ unsigned short Bhi_s[64][264];   // +8 pad: b128 reads conflict-free
    __shared__ unsigned short Blo_s[64][264];
    __shared__ float Scol[64];
    int b = blockIdx.x;
    int t = threadIdx.x;

    // ---- scatter prologue: 1 edge / thread (atomics retire under GEMM) ----
    {
        int e = b * 256 + t;
        int s = src[e], d = dst[e];
        int pos = atomicAdd(&cnt[s], 1);
        csr_dst[(s << 7) + pos] = d;
    }

    int m0 = (b >> 3) * 64;
    int n0 = (b & 7) * 64;
    if (t < 64) Scol[t] = 0.f;

    // ---- stage B tile (n0..n0+63, all 256 K) hi+lo into LDS ----
#pragma unroll
    for (int it = 0; it < 8; ++it) {
        int flat = it * 256 + t;       // 0..2047 dwordx4-units (32 per row)
        int row  = flat >> 5;
        int cu   = flat & 31;
        *(uint4*)(&Bhi_s[row][cu * 8]) =
            *(const uint4*)(WThi + (size_t)(n0 + row) * 256 + cu * 8);
        *(uint4*)(&Blo_s[row][cu * 8]) =
            *(const uint4*)(WTlo + (size_t)(n0 + row) * 256 + cu * 8);
    }
    __syncthreads();

    // ---- MFMA K-loop (no barriers) ----
    int w  = t >> 6;       // wave 0..3 -> rows m0+w*16..+15
    int l  = t & 63;
    int kg = l >> 4;       // k-group 0..3
    int ln = l & 15;
    int arow = m0 + w * 16 + ln;

    f32x4 acc[4] = {};     // 4 n-tiles

#pragma unroll
    for (int ks = 0; ks < 8; ++ks) {
        size_t aoff = (size_t)arow * 256 + ks * 32 + kg * 8;
        float4 v0 = *(const float4*)(xf + aoff);
        float4 v1 = *(const float4*)(xf + aoff + 4);
        float fv[8] = {v0.x, v0.y, v0.z, v0.w, v1.x, v1.y, v1.z, v1.w};
        bf16x8 ahi, alo;
#pragma unroll
        for (int j = 0; j < 8; ++j) {
            unsigned short hi = f2b(fv[j]);
            ahi[j] = (short)hi;
            alo[j] = (short)f2b(fv[j] - b2f(hi));
        }
#pragma unroll
        for (int nt = 0; nt < 4; ++nt) {
            bf16x8 bhi = *(const bf16x8*)(&Bhi_s[nt * 16 + ln][ks * 32 + kg * 8]);
            bf16x8 blo = *(const bf16x8*)(&Blo_s[nt * 16 + ln][ks * 32 + kg * 8]);
            acc[nt] = __builtin_amdgcn_mfma_f32_16x16x32_bf16(ahi, bhi, acc[nt], 0, 0, 0);
            acc[nt] = __builtin_amdgcn_mfma_f32_16x16x32_bf16(ahi, blo, acc[nt], 0, 0, 0);
            acc[nt] = __builtin_amdgcn_mfma_f32_16x16x32_bf16(alo, bhi, acc[nt], 0, 0, 0);
        }
    }

    // ---- Whb store (bf16). C/D layout: col=ln, row=kg*4+i ----
#pragma unroll
    for (int nt = 0; nt < 4; ++nt)
#pragma unroll
        for (int i = 0; i < 4; ++i) {
            int row = m0 + w * 16 + kg * 4 + i;
            Whb[(size_t)row * HF + n0 + nt * 16 + ln] = f2b(acc[nt][i]);
        }

    // ---- alpha epilogue (fp32-exact): tile covers head h fully ----
    int h = n0 >> 6;
    float a1v[4], a2v[4];
#pragma unroll
    for (int nt = 0; nt < 4; ++nt) {
        a1v[nt] = a[nt * 16 + ln];
        a2v[nt] = a[OUT_F + nt * 16 + ln];
    }
#pragma unroll
    for (int i = 0; i < 4; ++i) {
        float p1 = acc[0][i] * a1v[0] + acc[1][i] * a1v[1] +
                   acc[2][i] * a1v[2] + acc[3][i] * a1v[3];
        float p2 = acc[0][i] * a2v[0] + acc[1][i] * a2v[1] +
                   acc[2][i] * a2v[2] + acc[3][i] * a2v[3];
#pragma unroll
        for (int mask = 1; mask < 16; mask <<= 1) {   // reduce over ln (cols)
            p1 += __shfl_xor(p1, mask);
            p2 += __shfl_xor(p2, mask);
        }
        if (ln == 0) {
            int node = m0 + w * 16 + kg * 4 + i;
            asrc[node * HH + h] = p1;
            adst[node * HH + h] = p2;
        }
    }

    // ---- column-sum epilogue ----
#pragma unroll
    for (int nt = 0; nt < 4; ++nt) {
        float cs = acc[nt][0] + acc[nt][1] + acc[nt][2] + acc[nt][3];
        cs += __shfl_xor(cs, 16);   // reduce over kg (rows)
        cs += __shfl_xor(cs, 32);
        if (kg == 0) atomicAdd(&Scol[nt * 16 + ln], cs);
    }
    __syncthreads();
    if (t < 64) atomicAdd(&S[n0 + t], Scol[t]);
}

// ---------------------------------------------------------------------------
// K2: per-node aggregation with in-LDS dedup + staged weights.
// out[i,h,f] = (S[h,f] + sum_unique w*Whb[m,h,f]) / (N + sum_unique w)
// 4096 blocks x 512 thr = 8 groups x 64 lanes; lane reads uint4 (8 bf16).
// 2-deep software pipeline on the Whb gather.
// ---------------------------------------------------------------------------
__global__ __launch_bounds__(512) void aggregate_kernel(const unsigned short* __restrict__ Whb,
                                                        const float* __restrict__ asrc,
                                                        const float* __restrict__ adst,
                                                        const float* __restrict__ S,
                                                        const int* __restrict__ cnt,
                                                        const int* __restrict__ csr_dst,
                                                        float* __restrict__ out) {
    __shared__ int           midx[CAP];
    __shared__ unsigned char dupf[CAP];
    __shared__ float         wbuf[CAP * HH];   // 4 KB
    __shared__ float         as_sh[HH];
    __shared__ float         denom[HH];
    __shared__ float         red[8][HF];       // 16 KB
    int i = blockIdx.x;
    int t = threadIdx.x;                       // 0..511
    int deg = cnt[i];
    if (deg > CAP) deg = CAP;

    if (t < HH) as_sh[t] = asrc[i * HH + t];
    for (int j = t; j < deg; j += 512) midx[j] = csr_dst[(i << 7) + j];
    __syncthreads();

    // duplicate scan: slot j is dup iff an earlier slot holds the same index
    for (int j = t; j < deg; j += 512) {
        int m = midx[j];
        unsigned char f = 0;
        for (int k = 0; k < j; ++k)
            if (midx[k] == m) { f = 1; break; }
        dupf[j] = f;
    }
    __syncthreads();

    // staged parallel weights: thread per (slot, head)
    for (int idx = t; idx < deg * HH; idx += 512) {
        int sl = idx >> 3, h = idx & 7;
        float w = 0.f;
        if (!dupf[sl]) {
            float xv = as_sh[h] + adst[midx[sl] * HH + h];
            xv = (xv > 0.f) ? xv : 0.2f * xv;      // leaky_relu(., 0.2)
            w = __expf(xv) - 1.f;
        }
        wbuf[idx] = w;
    }
    __syncthreads();

    // per-head denominators
    if (t < 128) {
        int h = t >> 4, ln = t & 15;
        float p = 0.f;
        for (int sl = ln; sl < deg; sl += 16) p += wbuf[sl * HH + h];
#pragma unroll
        for (int mask = 1; mask < 16; mask <<= 1) p += __shfl_xor(p, mask);
        if (ln == 0) denom[h] = (float)NN + p;
    }
    __syncthreads();

    // main gather: 8 groups x 64 lanes, 16B/lane, 2-deep pipeline
    int g = t >> 6;
    int r = t & 63;
    int h = r >> 3;
    float accv[8] = {};

    int j0 = g, j1 = g + 8;
    uint4 u0 = {0, 0, 0, 0}, u1 = {0, 0, 0, 0};
    float w0 = 0.f, w1 = 0.f;
    if (j0 < deg) {
        w0 = wbuf[j0 * HH + h];
        u0 = *(const uint4*)(Whb + ((size_t)midx[j0] << 9) + (r << 3));
    }
    if (j1 < deg) {
        w1 = wbuf[j1 * HH + h];
        u1 = *(const uint4*)(Whb + ((size_t)midx[j1] << 9) + (r << 3));
    }
    int j = j0;
    while (j < deg) {
        int jn = j + 16;
        uint4 un = {0, 0, 0, 0};
        float wn = 0.f;
        if (jn < deg) {
            wn = wbuf[jn * HH + h];
            un = *(const uint4*)(Whb + ((size_t)midx[jn] << 9) + (r << 3));
        }
        accv[0] += w0 * b2f(u0.x & 0xFFFFu);
        accv[1] += w0 * b2f(u0.x >> 16);
        accv[2] += w0 * b2f(u0.y & 0xFFFFu);
        accv[3] += w0 * b2f(u0.y >> 16);
        accv[4] += w0 * b2f(u0.z & 0xFFFFu);
        accv[5] += w0 * b2f(u0.z >> 16);
        accv[6] += w0 * b2f(u0.w & 0xFFFFu);
        accv[7] += w0 * b2f(u0.w >> 16);
        u0 = u1; w0 = w1;
        u1 = un; w1 = wn;
        j += 8;
    }

    float4 v0 = {accv[0], accv[1], accv[2], accv[3]};
    float4 v1 = {accv[4], accv[5], accv[6], accv[7]};
    *(float4*)(&red[g][r * 8])     = v0;
    *(float4*)(&red[g][r * 8 + 4]) = v1;
    __syncthreads();

    float tot = S[t];
#pragma unroll
    for (int gg = 0; gg < 8; ++gg) tot += red[gg][t];
    out[((size_t)i << 9) + t] = tot / denom[t >> 6];
}

// ---------------------------------------------------------------------------
// launcher: 3 dispatches (prep, gemm+scatter, aggregate)
// ---------------------------------------------------------------------------
extern "C" void kernel_launch(void* const* d_in, const int* in_sizes, int n_in,
                              void* d_out, int out_size, void* d_ws, size_t ws_size,
                              hipStream_t stream) {
    const float* x  = (const float*)d_in[0];
    const float* W  = (const float*)d_in[1];
    const float* a  = (const float*)d_in[2];
    const int*   ei = (const int*)d_in[3];
    const int* src = ei;
    const int* dst = ei + EE;
    float* out = (float*)d_out;

    // workspace layout (bytes)
    char* ws = (char*)d_ws;
    unsigned short* Whb  = (unsigned short*)(ws + 0);          // 4,194,304
    unsigned short* WThi = (unsigned short*)(ws + 4194304);    // 262,144
    unsigned short* WTlo = (unsigned short*)(ws + 4456448);    // 262,144
    float* asrc     = (float*)(ws + 4718592);                  // 131,072
    float* adst     = (float*)(ws + 4849664);                  // 131,072
    int*   csr_dst  = (int*)  (ws + 4980736);                  // 2,097,152
    float* S        = (float*)(ws + 7077888);                  // 2,048
    int*   cnt      = (int*)  (ws + 7079936);                  // 16,384

    // K0: W transpose/convert + zero cnt/S
    prep<<<82, 256, 0, stream>>>(W, WThi, WTlo, S, cnt);

    // K1: scatter + MFMA GEMM (on-the-fly A convert) + alphas + column sums
    gemm_mfma<<<512, 256, 0, stream>>>(x, WThi, WTlo, a, src, dst,
                                       cnt, csr_dst, Whb, asrc, adst, S);

    // K2: aggregation (dedup + weights + gather)
    aggregate_kernel<<<NN, 512, 0, stream>>>(Whb, asrc, adst, S, cnt, csr_dst, out);
}

// Round 12
// 110.503 us; speedup vs baseline: 2.8993x; 1.0703x over previous
//
#include <hip/hip_runtime.h>
#include <hip/hip_bf16.h>

// Problem constants
constexpr int NN    = 4096;     // nodes
constexpr int EE    = 131072;   // edges
constexpr int IN_F  = 256;
constexpr int OUT_F = 64;
constexpr int HH    = 8;
constexpr int HF    = OUT_F * HH;   // 512
constexpr int CAP   = 128;          // CSR capacity (raw deg: mean 32, 17-sigma < 128)

typedef __attribute__((ext_vector_type(8))) short bf16x8;   // MFMA A/B frag
typedef __attribute__((ext_vector_type(4))) float f32x4;    // MFMA C/D frag

// f32 -> bf16 round-to-nearest-even
__device__ __forceinline__ unsigned short f2b(float f) {
    unsigned int u = __float_as_uint(f);
    u = u + 0x7FFFu + ((u >> 16) & 1u);
    return (unsigned short)(u >> 16);
}
// bf16 (as u16) -> f32 (exact)
__device__ __forceinline__ float b2f(unsigned int lo16) {
    return __uint_as_float(lo16 << 16);
}

// ---------------------------------------------------------------------------
// K1: scatter prologue + MFMA GEMM (split-bf16, 3 passes) + fused epilogues.
// 512 blocks x 256 thr (4 waves). Block b: tile (m0,n0)=((b>>3)*64,(b&7)*64).
// W column-slice read as fp32 and hi/lo-split DURING LDS staging (cold path,
// overlaps the scatter atomics). No barriers in the MFMA K-loop.
// A converted fp32->bf16 hi/lo on the fly from x (32B/lane/K-step, L2-hot).
// acc = xhi*Whi + xhi*Wlo + xlo*Whi  (~1e-5 rel error, fp32-equivalent here).
// ---------------------------------------------------------------------------
__global__ __launch_bounds__(256) void gemm_mfma(const float* __restrict__ xf,
                                                 const float* __restrict__ Wf,
                                                 const float* __restrict__ a,
                                                 const int* __restrict__ src,
                                                 const int* __restrict__ dst,
                                                 int* __restrict__ cnt,
                                                 int* __restrict__ csr_dst,
                                                 unsigned short* __restrict__ Whb,
                                                 float* __restrict__ asrc,
                                                 float* __restrict__ adst,
                                                 float* __restrict__ S) {
    __shared__ unsigned short Bhi_s[64][264];   // +8 pad: b128 reads conflict-free
    __shared__ unsigned short Blo_s[64][264];
    __shared__ float Scol[64];
    int b = blockIdx.x;
    int t = threadIdx.x;

    // ---- scatter prologue: 1 edge / thread (atomics retire under staging) ----
    {
        int e = b * 256 + t;
        int s = src[e], d = dst[e];
        int pos = atomicAdd(&cnt[s], 1);
        csr_dst[(s << 7) + pos] = d;
    }

    int m0 = (b >> 3) * 64;
    int n0 = (b & 7) * 64;
    if (t < 64) Scol[t] = 0.f;

    // ---- stage B tile: read W[k][n0..n0+63] fp32, split hi/lo into LDS ----
    // flat unit = (k, n4): 256 k x 16 float4-of-n = 4096 units / 256 thr = 16
#pragma unroll 4
    for (int it = 0; it < 16; ++it) {
        int flat = it * 256 + t;
        int k    = flat >> 4;           // 0..255
        int n4   = flat & 15;           // 0..15
        float4 v = *(const float4*)(Wf + (size_t)k * HF + n0 + n4 * 4);
        float fv[4] = {v.x, v.y, v.z, v.w};
#pragma unroll
        for (int j = 0; j < 4; ++j) {
            unsigned short hi = f2b(fv[j]);
            unsigned short lo = f2b(fv[j] - b2f(hi));
            Bhi_s[n4 * 4 + j][k] = hi;
            Blo_s[n4 * 4 + j][k] = lo;
        }
    }
    __syncthreads();

    // ---- MFMA K-loop (no barriers) ----
    int w  = t >> 6;       // wave 0..3 -> rows m0+w*16..+15
    int l  = t & 63;
    int kg = l >> 4;       // k-group 0..3
    int ln = l & 15;
    int arow = m0 + w * 16 + ln;

    f32x4 acc[4] = {};     // 4 n-tiles

#pragma unroll
    for (int ks = 0; ks < 8; ++ks) {
        size_t aoff = (size_t)arow * 256 + ks * 32 + kg * 8;
        float4 v0 = *(const float4*)(xf + aoff);
        float4 v1 = *(const float4*)(xf + aoff + 4);
        float fv[8] = {v0.x, v0.y, v0.z, v0.w, v1.x, v1.y, v1.z, v1.w};
        bf16x8 ahi, alo;
#pragma unroll
        for (int j = 0; j < 8; ++j) {
            unsigned short hi = f2b(fv[j]);
            ahi[j] = (short)hi;
            alo[j] = (short)f2b(fv[j] - b2f(hi));
        }
#pragma unroll
        for (int nt = 0; nt < 4; ++nt) {
            bf16x8 bhi = *(const bf16x8*)(&Bhi_s[nt * 16 + ln][ks * 32 + kg * 8]);
            bf16x8 blo = *(const bf16x8*)(&Blo_s[nt * 16 + ln][ks * 32 + kg * 8]);
            acc[nt] = __builtin_amdgcn_mfma_f32_16x16x32_bf16(ahi, bhi, acc[nt], 0, 0, 0);
            acc[nt] = __builtin_amdgcn_mfma_f32_16x16x32_bf16(ahi, blo, acc[nt], 0, 0, 0);
            acc[nt] = __builtin_amdgcn_mfma_f32_16x16x32_bf16(alo, bhi, acc[nt], 0, 0, 0);
        }
    }

    // ---- Whb store (bf16). C/D layout: col=ln, row=kg*4+i ----
#pragma unroll
    for (int nt = 0; nt < 4; ++nt)
#pragma unroll
        for (int i = 0; i < 4; ++i) {
            int row = m0 + w * 16 + kg * 4 + i;
            Whb[(size_t)row * HF + n0 + nt * 16 + ln] = f2b(acc[nt][i]);
        }

    // ---- alpha epilogue (fp32-exact): tile covers head h fully ----
    int h = n0 >> 6;
    float a1v[4], a2v[4];
#pragma unroll
    for (int nt = 0; nt < 4; ++nt) {
        a1v[nt] = a[nt * 16 + ln];
        a2v[nt] = a[OUT_F + nt * 16 + ln];
    }
#pragma unroll
    for (int i = 0; i < 4; ++i) {
        float p1 = acc[0][i] * a1v[0] + acc[1][i] * a1v[1] +
                   acc[2][i] * a1v[2] + acc[3][i] * a1v[3];
        float p2 = acc[0][i] * a2v[0] + acc[1][i] * a2v[1] +
                   acc[2][i] * a2v[2] + acc[3][i] * a2v[3];
#pragma unroll
        for (int mask = 1; mask < 16; mask <<= 1) {   // reduce over ln (cols)
            p1 += __shfl_xor(p1, mask);
            p2 += __shfl_xor(p2, mask);
        }
        if (ln == 0) {
            int node = m0 + w * 16 + kg * 4 + i;
            asrc[node * HH + h] = p1;
            adst[node * HH + h] = p2;
        }
    }

    // ---- column-sum epilogue ----
#pragma unroll
    for (int nt = 0; nt < 4; ++nt) {
        float cs = acc[nt][0] + acc[nt][1] + acc[nt][2] + acc[nt][3];
        cs += __shfl_xor(cs, 16);   // reduce over kg (rows)
        cs += __shfl_xor(cs, 32);
        if (kg == 0) atomicAdd(&Scol[nt * 16 + ln], cs);
    }
    __syncthreads();
    if (t < 64) atomicAdd(&S[n0 + t], Scol[t]);
}

// ---------------------------------------------------------------------------
// K2: per-node aggregation; dedup via LDS bitmap atomicOr (O(deg), exact:
// duplicates carry identical values, any single winner is correct).
// out[i,h,f] = (S[h,f] + sum_unique w*Whb[m,h,f]) / (N + sum_unique w)
// 4096 blocks x 512 thr = 8 groups x 64 lanes; lane reads uint4 (8 bf16).
// 2-deep software pipeline on the Whb gather.
// ---------------------------------------------------------------------------
__global__ __launch_bounds__(512) void aggregate_kernel(const unsigned short* __restrict__ Whb,
                                                        const float* __restrict__ asrc,
                                                        const float* __restrict__ adst,
                                                        const float* __restrict__ S,
                                                        const int* __restrict__ cnt,
                                                        const int* __restrict__ csr_dst,
                                                        float* __restrict__ out) {
    __shared__ int           midx[CAP];
    __shared__ unsigned char dupf[CAP];
    __shared__ unsigned int  bmap[NN / 32];    // 512 B
    __shared__ float         wbuf[CAP * HH];   // 4 KB
    __shared__ float         as_sh[HH];
    __shared__ float         denom[HH];
    __shared__ float         red[8][HF];       // 16 KB
    int i = blockIdx.x;
    int t = threadIdx.x;                       // 0..511
    int deg = cnt[i];
    if (deg > CAP) deg = CAP;

    if (t < NN / 32) bmap[t] = 0u;
    if (t < HH) as_sh[t] = asrc[i * HH + t];
    for (int j = t; j < deg; j += 512) midx[j] = csr_dst[(i << 7) + j];
    __syncthreads();

    // bitmap dedup: exactly one thread wins per unique index
    for (int j = t; j < deg; j += 512) {
        int m = midx[j];
        unsigned int old = atomicOr(&bmap[m >> 5], 1u << (m & 31));
        dupf[j] = (unsigned char)((old >> (m & 31)) & 1u);
    }
    __syncthreads();

    // staged parallel weights: thread per (slot, head)
    for (int idx = t; idx < deg * HH; idx += 512) {
        int sl = idx >> 3, h = idx & 7;
        float w = 0.f;
        if (!dupf[sl]) {
            float xv = as_sh[h] + adst[midx[sl] * HH + h];
            xv = (xv > 0.f) ? xv : 0.2f * xv;      // leaky_relu(., 0.2)
            w = __expf(xv) - 1.f;
        }
        wbuf[idx] = w;
    }
    __syncthreads();

    // per-head denominators
    if (t < 128) {
        int h = t >> 4, ln = t & 15;
        float p = 0.f;
        for (int sl = ln; sl < deg; sl += 16) p += wbuf[sl * HH + h];
#pragma unroll
        for (int mask = 1; mask < 16; mask <<= 1) p += __shfl_xor(p, mask);
        if (ln == 0) denom[h] = (float)NN + p;
    }
    __syncthreads();

    // main gather: 8 groups x 64 lanes, 16B/lane, 2-deep pipeline
    int g = t >> 6;
    int r = t & 63;
    int h = r >> 3;
    float accv[8] = {};

    int j0 = g, j1 = g + 8;
    uint4 u0 = {0, 0, 0, 0}, u1 = {0, 0, 0, 0};
    float w0 = 0.f, w1 = 0.f;
    if (j0 < deg) {
        w0 = wbuf[j0 * HH + h];
        u0 = *(const uint4*)(Whb + ((size_t)midx[j0] << 9) + (r << 3));
    }
    if (j1 < deg) {
        w1 = wbuf[j1 * HH + h];
        u1 = *(const uint4*)(Whb + ((size_t)midx[j1] << 9) + (r << 3));
    }
    int j = j0;
    while (j < deg) {
        int jn = j + 16;
        uint4 un = {0, 0, 0, 0};
        float wn = 0.f;
        if (jn < deg) {
            wn = wbuf[jn * HH + h];
            un = *(const uint4*)(Whb + ((size_t)midx[jn] << 9) + (r << 3));
        }
        accv[0] += w0 * b2f(u0.x & 0xFFFFu);
        accv[1] += w0 * b2f(u0.x >> 16);
        accv[2] += w0 * b2f(u0.y & 0xFFFFu);
        accv[3] += w0 * b2f(u0.y >> 16);
        accv[4] += w0 * b2f(u0.z & 0xFFFFu);
        accv[5] += w0 * b2f(u0.z >> 16);
        accv[6] += w0 * b2f(u0.w & 0xFFFFu);
        accv[7] += w0 * b2f(u0.w >> 16);
        u0 = u1; w0 = w1;
        u1 = un; w1 = wn;
        j += 8;
    }

    float4 v0 = {accv[0], accv[1], accv[2], accv[3]};
    float4 v1 = {accv[4], accv[5], accv[6], accv[7]};
    *(float4*)(&red[g][r * 8])     = v0;
    *(float4*)(&red[g][r * 8 + 4]) = v1;
    __syncthreads();

    float tot = S[t];
#pragma unroll
    for (int gg = 0; gg < 8; ++gg) tot += red[gg][t];
    out[((size_t)i << 9) + t] = tot / denom[t >> 6];
}

// ---------------------------------------------------------------------------
// launcher: tiny memset + 2 kernel dispatches
// ---------------------------------------------------------------------------
extern "C" void kernel_launch(void* const* d_in, const int* in_sizes, int n_in,
                              void* d_out, int out_size, void* d_ws, size_t ws_size,
                              hipStream_t stream) {
    const float* x  = (const float*)d_in[0];
    const float* W  = (const float*)d_in[1];
    const float* a  = (const float*)d_in[2];
    const int*   ei = (const int*)d_in[3];
    const int* src = ei;
    const int* dst = ei + EE;
    float* out = (float*)d_out;

    // workspace layout (bytes)
    char* ws = (char*)d_ws;
    unsigned short* Whb = (unsigned short*)(ws + 0);   // 4,194,304
    float* asrc     = (float*)(ws + 4194304);          // 131,072
    float* adst     = (float*)(ws + 4325376);          // 131,072
    int*   csr_dst  = (int*)  (ws + 4456448);          // 2,097,152
    float* S        = (float*)(ws + 6553600);          // 2,048
    int*   cnt      = (int*)  (ws + 6555648);          // 16,384

    // zero S + cnt (contiguous, 18.4 KB, latency-only)
    hipMemsetAsync(ws + 6553600, 0, 2048 + 16384, stream);

    // K1: scatter + MFMA GEMM (in-kernel W convert) + alphas + column sums
    gemm_mfma<<<512, 256, 0, stream>>>(x, W, a, src, dst,
                                       cnt, csr_dst, Whb, asrc, adst, S);

    // K2: aggregation (bitmap dedup + staged weights + gather)
    aggregate_kernel<<<NN, 512, 0, stream>>>(Whb, asrc, adst, S, cnt, csr_dst, out);
}

// Round 13
// 105.834 us; speedup vs baseline: 3.0272x; 1.0441x over previous
//
#include <hip/hip_runtime.h>
#include <hip/hip_bf16.h>

// Problem constants
constexpr int NN    = 4096;     // nodes
constexpr int EE    = 131072;   // edges
constexpr int IN_F  = 256;
constexpr int OUT_F = 64;
constexpr int HH    = 8;
constexpr int HF    = OUT_F * HH;   // 512
constexpr int CAP   = 128;          // CSR capacity (raw deg: mean 32, 17-sigma < 128)

typedef __attribute__((ext_vector_type(8))) short bf16x8;   // MFMA A/B frag
typedef __attribute__((ext_vector_type(4))) float f32x4;    // MFMA C/D frag

// f32 -> bf16 round-to-nearest-even
__device__ __forceinline__ unsigned short f2b(float f) {
    unsigned int u = __float_as_uint(f);
    u = u + 0x7FFFu + ((u >> 16) & 1u);
    return (unsigned short)(u >> 16);
}
// bf16 (as u16) -> f32 (exact)
__device__ __forceinline__ float b2f(unsigned int lo16) {
    return __uint_as_float(lo16 << 16);
}

// ---------------------------------------------------------------------------
// K1: scatter prologue + MFMA GEMM (split-bf16, 3 passes) + fused epilogues.
// 512 blocks x 256 thr (4 waves). Block b: tile (m0,n0)=((b>>3)*64,(b&7)*64).
// W column-slice read as fp32 and hi/lo-split DURING LDS staging (cold path,
// overlaps the scatter atomics). No barriers in the MFMA K-loop.
// A converted fp32->bf16 hi/lo on the fly from x (32B/lane/K-step, L2-hot).
// acc = xhi*Whi + xhi*Wlo + xlo*Whi  (~1e-5 rel error, fp32-equivalent here).
// ---------------------------------------------------------------------------
__global__ __launch_bounds__(256) void gemm_mfma(const float* __restrict__ xf,
                                                 const float* __restrict__ Wf,
                                                 const float* __restrict__ a,
                                                 const int* __restrict__ src,
                                                 const int* __restrict__ dst,
                                                 int* __restrict__ cnt,
                                                 int* __restrict__ csr_dst,
                                                 unsigned short* __restrict__ Whb,
                                                 float* __restrict__ asrc,
                                                 float* __restrict__ adst,
                                                 float* __restrict__ S) {
    __shared__ unsigned short Bhi_s[64][264];   // +8 pad: b128 reads conflict-free
    __shared__ unsigned short Blo_s[64][264];
    __shared__ float Scol[64];
    int b = blockIdx.x;
    int t = threadIdx.x;

    // ---- scatter prologue: 1 edge / thread (atomics retire under staging) ----
    {
        int e = b * 256 + t;
        int s = src[e], d = dst[e];
        int pos = atomicAdd(&cnt[s], 1);
        csr_dst[(s << 7) + pos] = d;
    }

    int m0 = (b >> 3) * 64;
    int n0 = (b & 7) * 64;
    if (t < 64) Scol[t] = 0.f;

    // ---- stage B tile: read W[k][n0..n0+63] fp32, split hi/lo into LDS ----
#pragma unroll 4
    for (int it = 0; it < 16; ++it) {
        int flat = it * 256 + t;
        int k    = flat >> 4;           // 0..255
        int n4   = flat & 15;           // 0..15
        float4 v = *(const float4*)(Wf + (size_t)k * HF + n0 + n4 * 4);
        float fv[4] = {v.x, v.y, v.z, v.w};
#pragma unroll
        for (int j = 0; j < 4; ++j) {
            unsigned short hi = f2b(fv[j]);
            unsigned short lo = f2b(fv[j] - b2f(hi));
            Bhi_s[n4 * 4 + j][k] = hi;
            Blo_s[n4 * 4 + j][k] = lo;
        }
    }
    __syncthreads();

    // ---- MFMA K-loop (no barriers) ----
    int w  = t >> 6;       // wave 0..3 -> rows m0+w*16..+15
    int l  = t & 63;
    int kg = l >> 4;       // k-group 0..3
    int ln = l & 15;
    int arow = m0 + w * 16 + ln;

    f32x4 acc[4] = {};     // 4 n-tiles

#pragma unroll
    for (int ks = 0; ks < 8; ++ks) {
        size_t aoff = (size_t)arow * 256 + ks * 32 + kg * 8;
        float4 v0 = *(const float4*)(xf + aoff);
        float4 v1 = *(const float4*)(xf + aoff + 4);
        float fv[8] = {v0.x, v0.y, v0.z, v0.w, v1.x, v1.y, v1.z, v1.w};
        bf16x8 ahi, alo;
#pragma unroll
        for (int j = 0; j < 8; ++j) {
            unsigned short hi = f2b(fv[j]);
            ahi[j] = (short)hi;
            alo[j] = (short)f2b(fv[j] - b2f(hi));
        }
#pragma unroll
        for (int nt = 0; nt < 4; ++nt) {
            bf16x8 bhi = *(const bf16x8*)(&Bhi_s[nt * 16 + ln][ks * 32 + kg * 8]);
            bf16x8 blo = *(const bf16x8*)(&Blo_s[nt * 16 + ln][ks * 32 + kg * 8]);
            acc[nt] = __builtin_amdgcn_mfma_f32_16x16x32_bf16(ahi, bhi, acc[nt], 0, 0, 0);
            acc[nt] = __builtin_amdgcn_mfma_f32_16x16x32_bf16(ahi, blo, acc[nt], 0, 0, 0);
            acc[nt] = __builtin_amdgcn_mfma_f32_16x16x32_bf16(alo, bhi, acc[nt], 0, 0, 0);
        }
    }

    // ---- Whb store (bf16). C/D layout: col=ln, row=kg*4+i ----
#pragma unroll
    for (int nt = 0; nt < 4; ++nt)
#pragma unroll
        for (int i = 0; i < 4; ++i) {
            int row = m0 + w * 16 + kg * 4 + i;
            Whb[(size_t)row * HF + n0 + nt * 16 + ln] = f2b(acc[nt][i]);
        }

    // ---- alpha epilogue (fp32-exact): tile covers head h fully ----
    int h = n0 >> 6;
    float a1v[4], a2v[4];
#pragma unroll
    for (int nt = 0; nt < 4; ++nt) {
        a1v[nt] = a[nt * 16 + ln];
        a2v[nt] = a[OUT_F + nt * 16 + ln];
    }
#pragma unroll
    for (int i = 0; i < 4; ++i) {
        float p1 = acc[0][i] * a1v[0] + acc[1][i] * a1v[1] +
                   acc[2][i] * a1v[2] + acc[3][i] * a1v[3];
        float p2 = acc[0][i] * a2v[0] + acc[1][i] * a2v[1] +
                   acc[2][i] * a2v[2] + acc[3][i] * a2v[3];
#pragma unroll
        for (int mask = 1; mask < 16; mask <<= 1) {   // reduce over ln (cols)
            p1 += __shfl_xor(p1, mask);
            p2 += __shfl_xor(p2, mask);
        }
        if (ln == 0) {
            int node = m0 + w * 16 + kg * 4 + i;
            asrc[node * HH + h] = p1;
            adst[node * HH + h] = p2;
        }
    }

    // ---- column-sum epilogue ----
#pragma unroll
    for (int nt = 0; nt < 4; ++nt) {
        float cs = acc[nt][0] + acc[nt][1] + acc[nt][2] + acc[nt][3];
        cs += __shfl_xor(cs, 16);   // reduce over kg (rows)
        cs += __shfl_xor(cs, 32);
        if (kg == 0) atomicAdd(&Scol[nt * 16 + ln], cs);
    }
    __syncthreads();
    if (t < 64) atomicAdd(&S[n0 + t], Scol[t]);
}

// ---------------------------------------------------------------------------
// K2: wave-per-node aggregation. 4096 blocks x 64 threads (1 wave = 1 node).
// Lane l owns features l*8..l*8+7 (one uint4 of the Whb row -> a full row
// load is ONE coalesced 1KB wave instruction). All sync is single-wave
// __syncthreads (near-free). acc stays in registers (no LDS reduce).
// Denominator is free: every lane of head h accumulates z += w[j][h] in the
// gather loop, so all lanes end holding the full per-head sum.
// Dedup: LDS bitmap atomicOr; winner lane computes all 8 head weights.
// ---------------------------------------------------------------------------
__global__ __launch_bounds__(64) void aggregate_kernel(const unsigned short* __restrict__ Whb,
                                                       const float* __restrict__ asrc,
                                                       const float* __restrict__ adst,
                                                       const float* __restrict__ S,
                                                       const int* __restrict__ cnt,
                                                       const int* __restrict__ csr_dst,
                                                       float* __restrict__ out) {
    __shared__ int          midx[CAP];         // 512 B
    __shared__ unsigned int bmap[NN / 32];     // 512 B
    __shared__ float        wbuf[CAP * HH];    // 4 KB
    int i = blockIdx.x;
    int l = threadIdx.x;                       // 0..63
    int deg = cnt[i];
    if (deg > CAP) deg = CAP;

    // zero bitmap (2 words/lane) + load midx (2 slots/lane)
    bmap[l] = 0u;
    bmap[l + 64] = 0u;
    if (l < deg)      midx[l]      = csr_dst[(i << 7) + l];
    if (l + 64 < deg) midx[l + 64] = csr_dst[(i << 7) + l + 64];
    __syncthreads();

    // dedup + weights: lane per slot; winner computes all 8 head weights
    float4 s0 = *(const float4*)(asrc + i * HH);        // broadcast
    float4 s1 = *(const float4*)(asrc + i * HH + 4);
    for (int j = l; j < deg; j += 64) {
        int m = midx[j];
        unsigned int old = atomicOr(&bmap[m >> 5], 1u << (m & 31));
        if ((old >> (m & 31)) & 1u) {
            // duplicate: zero weights
            *(float4*)(&wbuf[j * HH])     = make_float4(0.f, 0.f, 0.f, 0.f);
            *(float4*)(&wbuf[j * HH + 4]) = make_float4(0.f, 0.f, 0.f, 0.f);
        } else {
            float4 d0 = *(const float4*)(adst + m * HH);
            float4 d1 = *(const float4*)(adst + m * HH + 4);
            float ev[8] = {s0.x + d0.x, s0.y + d0.y, s0.z + d0.z, s0.w + d0.w,
                           s1.x + d1.x, s1.y + d1.y, s1.z + d1.z, s1.w + d1.w};
            float w[8];
#pragma unroll
            for (int h = 0; h < 8; ++h) {
                float xv = ev[h];
                xv = (xv > 0.f) ? xv : 0.2f * xv;      // leaky_relu(., 0.2)
                w[h] = __expf(xv) - 1.f;
            }
            *(float4*)(&wbuf[j * HH])     = make_float4(w[0], w[1], w[2], w[3]);
            *(float4*)(&wbuf[j * HH + 4]) = make_float4(w[4], w[5], w[6], w[7]);
        }
    }
    __syncthreads();

    // gather: serial over deg, 2-deep pipeline; 16B/lane = 1KB/row/wave
    int h = l >> 3;                    // head of this lane's feature slice
    float accv[8] = {};
    float z = 0.f;

    int j0 = 0, j1 = 1;
    uint4 u0 = {0, 0, 0, 0}, u1 = {0, 0, 0, 0};
    float w0 = 0.f, w1 = 0.f;
    if (j0 < deg) {
        w0 = wbuf[j0 * HH + h];
        u0 = *(const uint4*)(Whb + ((size_t)midx[j0] << 9) + (l << 3));
    }
    if (j1 < deg) {
        w1 = wbuf[j1 * HH + h];
        u1 = *(const uint4*)(Whb + ((size_t)midx[j1] << 9) + (l << 3));
    }
    for (int j = 0; j < deg; ++j) {
        int jn = j + 2;
        uint4 un = {0, 0, 0, 0};
        float wn = 0.f;
        if (jn < deg) {
            wn = wbuf[jn * HH + h];
            un = *(const uint4*)(Whb + ((size_t)midx[jn] << 9) + (l << 3));
        }
        z += w0;
        accv[0] += w0 * b2f(u0.x & 0xFFFFu);
        accv[1] += w0 * b2f(u0.x >> 16);
        accv[2] += w0 * b2f(u0.y & 0xFFFFu);
        accv[3] += w0 * b2f(u0.y >> 16);
        accv[4] += w0 * b2f(u0.z & 0xFFFFu);
        accv[5] += w0 * b2f(u0.z >> 16);
        accv[6] += w0 * b2f(u0.w & 0xFFFFu);
        accv[7] += w0 * b2f(u0.w >> 16);
        u0 = u1; w0 = w1;
        u1 = un; w1 = wn;
    }

    // output: lane's 8 features; denom = N + z (complete in every lane)
    float rz = 1.f / ((float)NN + z);
    float4 S0 = *(const float4*)(S + l * 8);
    float4 S1 = *(const float4*)(S + l * 8 + 4);
    float4 o0 = {(S0.x + accv[0]) * rz, (S0.y + accv[1]) * rz,
                 (S0.z + accv[2]) * rz, (S0.w + accv[3]) * rz};
    float4 o1 = {(S1.x + accv[4]) * rz, (S1.y + accv[5]) * rz,
                 (S1.z + accv[6]) * rz, (S1.w + accv[7]) * rz};
    *(float4*)(out + ((size_t)i << 9) + l * 8)     = o0;
    *(float4*)(out + ((size_t)i << 9) + l * 8 + 4) = o1;
}

// ---------------------------------------------------------------------------
// launcher: tiny memset + 2 kernel dispatches
// ---------------------------------------------------------------------------
extern "C" void kernel_launch(void* const* d_in, const int* in_sizes, int n_in,
                              void* d_out, int out_size, void* d_ws, size_t ws_size,
                              hipStream_t stream) {
    const float* x  = (const float*)d_in[0];
    const float* W  = (const float*)d_in[1];
    const float* a  = (const float*)d_in[2];
    const int*   ei = (const int*)d_in[3];
    const int* src = ei;
    const int* dst = ei + EE;
    float* out = (float*)d_out;

    // workspace layout (bytes)
    char* ws = (char*)d_ws;
    unsigned short* Whb = (unsigned short*)(ws + 0);   // 4,194,304
    float* asrc     = (float*)(ws + 4194304);          // 131,072
    float* adst     = (float*)(ws + 4325376);          // 131,072
    int*   csr_dst  = (int*)  (ws + 4456448);          // 2,097,152
    float* S        = (float*)(ws + 6553600);          // 2,048
    int*   cnt      = (int*)  (ws + 6555648);          // 16,384

    // zero S + cnt (contiguous, 18.4 KB, latency-only)
    hipMemsetAsync(ws + 6553600, 0, 2048 + 16384, stream);

    // K1: scatter + MFMA GEMM (in-kernel W convert) + alphas + column sums
    gemm_mfma<<<512, 256, 0, stream>>>(x, W, a, src, dst,
                                       cnt, csr_dst, Whb, asrc, adst, S);

    // K2: wave-per-node aggregation (bitmap dedup + in-register gather)
    aggregate_kernel<<<NN, 64, 0, stream>>>(Whb, asrc, adst, S, cnt, csr_dst, out);
}